// Round 5
// baseline (3569.366 us; speedup 1.0000x reference)
//
#include <hip/hip_runtime.h>

#define BB 128
#define TT 2048
#define HH 64

__device__ __forceinline__ float sigm(float v) {
    return __builtin_amdgcn_rcpf(1.0f + __expf(-v));
}
__device__ __forceinline__ float ftanh(float v) {
    float e = __expf(-2.0f * fabsf(v));
    float r = (1.0f - e) * __builtin_amdgcn_rcpf(1.0f + e);
    return copysignf(r, v);
}

#define PIN4(v) asm volatile("" : "+v"((v).x), "+v"((v).y), "+v"((v).z), "+v"((v).w))

// One block per batch, 9 waves. Row-split: 576 recurrent rows (Whh0,Wih1,Whh1
// x 192) / 576 lanes -> each lane owns ONE row = 16 float4 = 64 VGPRs of
// weights. This fits under the ~120-VGPR allocation the RA insists on
// (R2-R4: 192 floats/lane always spilled -> L2-bound at 147KB/block/iter).
//
// Per iteration i (2 barriers):
//  Phase A (9 waves): lane dot W[row]·h + b[row]
//     waves 0-2: hg1(i)   = Whh0·h1[i-1]+bhh0
//     waves 3-5: xg(i-1)  = Wih1·h1[i-1]+bih1   (parity buffer)
//     waves 6-8: hg2(i-2) = Whh1·h2[i-3]+bhh1
//  Phase B: wave0 -> h1[i] gates; wave3 -> h2[i-2] gates + ring store;
//           wave6 -> fc-head flush of 64 outputs every 64 iters.
__global__ __launch_bounds__(576, 2)
void gru_fused(const float* __restrict__ x,
               const float* __restrict__ Wih0, const float* __restrict__ Whh0,
               const float* __restrict__ bih0, const float* __restrict__ bhh0,
               const float* __restrict__ Wih1, const float* __restrict__ Whh1,
               const float* __restrict__ bih1, const float* __restrict__ bhh1,
               const float* __restrict__ fcw, const float* __restrict__ fcb,
               float* __restrict__ out)
{
    const int t  = threadIdx.x;
    const int wv = t >> 6;          // wave id 0..8
    const int j  = t & 63;          // lane
    const int b  = blockIdx.x;

    __shared__ __align__(16) float xs[TT * 2];      // 16 KB input
    __shared__ __align__(16) float h1b[HH];
    __shared__ __align__(16) float h2b[HH];
    __shared__ __align__(16) float hg1[3 * HH];
    __shared__ __align__(16) float hg2[3 * HH];
    __shared__ __align__(16) float xgb[2][3 * HH];  // parity
    __shared__ __align__(16) float fwS[HH];
    __shared__ float ring[128][65];                 // h2 history, stride 65

    // ---- this lane's single weight row (64 floats = 16 float4) ----
    const int g = (wv < 3) ? wv : (wv < 6) ? wv - 3 : wv - 6;   // gate block
    const float* Wm = (wv < 3) ? Whh0 : (wv < 6) ? Wih1 : Whh1;
    const float* bm = (wv < 3) ? bhh0 : (wv < 6) ? bih1 : bhh1;
    const int row = g * HH + j;
    float4 w[16];
    {
        const float4* p = (const float4*)(Wm + (size_t)row * HH);
        #pragma unroll
        for (int k = 0; k < 16; ++k) w[k] = p[k];
    }
    #pragma unroll
    for (int k = 0; k < 16; ++k) PIN4(w[k]);
    const float brow = bm[row];

    // wave-0 layer-1 input-side constants
    float wi0=0, wi1=0, wi2=0, wi3=0, wi4=0, wi5=0, bi0=0, bi1=0, bi2=0;
    if (wv == 0) {
        wi0 = Wih0[j*2];          wi1 = Wih0[j*2 + 1];
        wi2 = Wih0[(HH+j)*2];     wi3 = Wih0[(HH+j)*2 + 1];
        wi4 = Wih0[(2*HH+j)*2];   wi5 = Wih0[(2*HH+j)*2 + 1];
        bi0 = bih0[j]; bi1 = bih0[HH + j]; bi2 = bih0[2*HH + j];
    }
    const float fcbv = fcb[0];

    // ---- preload x, zero state ----
    {
        const float4* xp  = (const float4*)(x + (size_t)b * TT * 2);
        float4*       xsp = (float4*)xs;
        for (int i2 = t; i2 < TT * 2 / 4; i2 += 576) xsp[i2] = xp[i2];
    }
    if (t < HH) { h1b[t] = 0.f; h2b[t] = 0.f; fwS[t] = fcw[t]; }

    float h1reg = 0.f;   // wave0 lane j: h1[j]
    float h2reg = 0.f;   // wave3 lane j: h2[j]
    __syncthreads();

    for (int i = 0; i < TT + 2; ++i) {
        // ---------------- Phase A: 576 parallel row-dots ----------------
        const bool actA = (wv < 3) ? (i < TT)
                        : (wv < 6) ? (i >= 1 && i <= TT)
                                   : (i >= 2);
        if (actA) {
            const float4* hb = (wv < 6) ? (const float4*)h1b
                                        : (const float4*)h2b;
            float a0 = brow, a1 = 0.f, a2 = 0.f, a3 = 0.f;
            #pragma unroll
            for (int k = 0; k < 16; k += 4) {
                float4 hA = hb[k], hB = hb[k+1], hC = hb[k+2], hD = hb[k+3];
                a0 += w[k  ].x*hA.x + w[k  ].y*hA.y + w[k  ].z*hA.z + w[k  ].w*hA.w;
                a1 += w[k+1].x*hB.x + w[k+1].y*hB.y + w[k+1].z*hB.z + w[k+1].w*hB.w;
                a2 += w[k+2].x*hC.x + w[k+2].y*hC.y + w[k+2].z*hC.z + w[k+2].w*hC.w;
                a3 += w[k+3].x*hD.x + w[k+3].y*hD.y + w[k+3].z*hD.z + w[k+3].w*hD.w;
            }
            const float dot = (a0 + a1) + (a2 + a3);
            if (wv < 3)      hg1[row] = dot;
            else if (wv < 6) xgb[(i - 1) & 1][row] = dot;
            else             hg2[row] = dot;
        }
        __syncthreads();

        // ---------------- Phase B: gate combines ----------------
        if (wv == 0) {
            if (i < TT) {                         // layer-1 step i
                float x0 = xs[2*i], x1 = xs[2*i + 1];
                float r = sigm (wi0*x0 + wi1*x1 + bi0 + hg1[j]);
                float z = sigm (wi2*x0 + wi3*x1 + bi1 + hg1[HH + j]);
                float n = ftanh(wi4*x0 + wi5*x1 + bi2 + r * hg1[2*HH + j]);
                h1reg = (1.f - z) * n + z * h1reg;
                h1b[j] = h1reg;
            }
        } else if (wv == 3) {
            if (i >= 2) {                         // layer-2 step i-2
                const float* xg = xgb[(i - 2) & 1];
                float r = sigm (xg[j]        + hg2[j]);
                float z = sigm (xg[HH + j]   + hg2[HH + j]);
                float n = ftanh(xg[2*HH + j] + r * hg2[2*HH + j]);
                h2reg = (1.f - z) * n + z * h2reg;
                h2b[j] = h2reg;
                ring[(i - 2) & 127][j] = h2reg;
            }
        } else if (wv == 6) {
            if (i >= 66 && ((i - 66) & 63) == 0) {   // flush chunk c
                const int tt = ((i - 66) >> 6) * 64 + j;
                const float* rr = ring[tt & 127];
                float acc0 = 0.f, acc1 = 0.f;
                #pragma unroll
                for (int k = 0; k < 64; k += 2) {
                    acc0 += rr[k]     * fwS[k];
                    acc1 += rr[k + 1] * fwS[k + 1];
                }
                out[(size_t)b * TT + tt] = acc0 + acc1 + fcbv;
            }
        }
        __syncthreads();
    }

    // final chunk: steps 1984..2047
    if (wv == 6) {
        const int tt = 31 * 64 + j;
        const float* rr = ring[tt & 127];
        float acc0 = 0.f, acc1 = 0.f;
        #pragma unroll
        for (int k = 0; k < 64; k += 2) {
            acc0 += rr[k]     * fwS[k];
            acc1 += rr[k + 1] * fwS[k + 1];
        }
        out[(size_t)b * TT + tt] = acc0 + acc1 + fcbv;
    }
}

extern "C" void kernel_launch(void* const* d_in, const int* in_sizes, int n_in,
                              void* d_out, int out_size, void* d_ws, size_t ws_size,
                              hipStream_t stream) {
    const float* x    = (const float*)d_in[0];
    const float* Wih0 = (const float*)d_in[1];
    const float* Whh0 = (const float*)d_in[2];
    const float* bih0 = (const float*)d_in[3];
    const float* bhh0 = (const float*)d_in[4];
    const float* Wih1 = (const float*)d_in[5];
    const float* Whh1 = (const float*)d_in[6];
    const float* bih1 = (const float*)d_in[7];
    const float* bhh1 = (const float*)d_in[8];
    const float* fcw  = (const float*)d_in[9];
    const float* fcb  = (const float*)d_in[10];
    float* out = (float*)d_out;

    gru_fused<<<BB, 576, 0, stream>>>(x, Wih0, Whh0, bih0, bhh0,
                                      Wih1, Whh1, bih1, bhh1, fcw, fcb, out);
}

// Round 6
// 2357.222 us; speedup vs baseline: 1.5142x; 1.5142x over previous
//
#include <hip/hip_runtime.h>

#define BB 128
#define TT 2048
#define HH 64

__device__ __forceinline__ float sigm(float v) {
    return __builtin_amdgcn_rcpf(1.0f + __expf(-v));
}
__device__ __forceinline__ float ftanh(float v) {
    float e = __expf(-2.0f * fabsf(v));
    float r = (1.0f - e) * __builtin_amdgcn_rcpf(1.0f + e);
    return copysignf(r, v);
}

// Weights live in AGPRs: the VGPR allocator capped at ~120-132 regs (R2-R4)
// and rematerialized 192 weight floats from L2 every timestep. "a"-constraint
// pins give the allocator no discretion; each use is one v_accvgpr_read_b32.
#define APIN(x)     asm volatile("" : "+a"(x))
#define ARD(d, s)   asm("v_accvgpr_read_b32 %0, %1" : "=v"(d) : "a"(s))
// acc += dot(wA[base..base+3], hv)
#define DOT4(acc, base, hv) do {                                           \
    float t0_, t1_, t2_, t3_;                                              \
    ARD(t0_, wA[(base)    ]); ARD(t1_, wA[(base) + 1]);                    \
    ARD(t2_, wA[(base) + 2]); ARD(t3_, wA[(base) + 3]);                    \
    acc = fmaf(t0_, (hv).x, fmaf(t1_, (hv).y,                              \
          fmaf(t2_, (hv).z, fmaf(t3_, (hv).w, acc))));                     \
} while (0)

// One block per batch. 3 waves (R2 structure, verified correct):
//   wave0: h1(i)   = GRU1(h1(i-1), x(i))        [hg1 in registers]
//   wave1: xg(i-1) = Wih1*h1(i-1)+bih1          [parity LDS buffer]
//   wave2: h2(i-2) = GRU2(h2(i-3), xg(i-2))     [hg2 in registers]
// Single barrier per iteration; each wave reads only LDS written in previous
// iterations. fc head: wave2 -> 128-slot ring; wave1 flushes 64 every 64 it.
__global__ __launch_bounds__(192)
__attribute__((amdgpu_waves_per_eu(1, 1)))
void gru_fused(const float* __restrict__ x,
               const float* __restrict__ Wih0, const float* __restrict__ Whh0,
               const float* __restrict__ bih0, const float* __restrict__ bhh0,
               const float* __restrict__ Wih1, const float* __restrict__ Whh1,
               const float* __restrict__ bih1, const float* __restrict__ bhh1,
               const float* __restrict__ fcw, const float* __restrict__ fcb,
               float* __restrict__ out)
{
    const int t  = threadIdx.x;
    const int wv = t >> 6;          // wave id 0..2
    const int j  = t & 63;          // lane
    const int b  = blockIdx.x;

    __shared__ __align__(16) float xs[TT * 2];        // 16 KB input
    __shared__ __align__(16) float h1b[2][HH];        // parity buffers
    __shared__ __align__(16) float h2b[HH];           // wave2-private
    __shared__ __align__(16) float xgb[2][3 * HH];    // parity buffers
    __shared__ __align__(16) float fwS[HH];
    __shared__ float ring[128][65];                   // h2 history, stride 65

    // ---- this wave's 3 rows (j, 64+j, 128+j) -> 192 floats in AGPRs ----
    const float* Wm = (wv == 0) ? Whh0 : (wv == 1) ? Wih1 : Whh1;
    float wA[192];
    #pragma unroll
    for (int r = 0; r < 3; ++r) {
        const float4* p = (const float4*)(Wm + (size_t)(r * HH + j) * HH);
        #pragma unroll
        for (int k = 0; k < 16; ++k) {
            float4 v = p[k];
            wA[r * 64 + 4 * k + 0] = v.x; wA[r * 64 + 4 * k + 1] = v.y;
            wA[r * 64 + 4 * k + 2] = v.z; wA[r * 64 + 4 * k + 3] = v.w;
        }
    }
    #pragma unroll
    for (int e = 0; e < 192; ++e) APIN(wA[e]);

    // dot-phase biases
    float ba, bbv, bc;
    if (wv == 0)      { ba = bhh0[j]; bbv = bhh0[HH + j]; bc = bhh0[2*HH + j]; }
    else if (wv == 1) { ba = bih1[j]; bbv = bih1[HH + j]; bc = bih1[2*HH + j]; }
    else              { ba = bhh1[j]; bbv = bhh1[HH + j]; bc = bhh1[2*HH + j]; }
    // wave0 input-side constants
    float wi0=0, wi1=0, wi2=0, wi3=0, wi4=0, wi5=0, bi0=0, bi1=0, bi2=0;
    if (wv == 0) {
        wi0 = Wih0[j*2];          wi1 = Wih0[j*2 + 1];
        wi2 = Wih0[(HH+j)*2];     wi3 = Wih0[(HH+j)*2 + 1];
        wi4 = Wih0[(2*HH+j)*2];   wi5 = Wih0[(2*HH+j)*2 + 1];
        bi0 = bih0[j]; bi1 = bih0[HH + j]; bi2 = bih0[2*HH + j];
    }
    const float fcbv = fcb[0];

    // ---- preload x, zero state ----
    {
        const float4* xp  = (const float4*)(x + (size_t)b * TT * 2);
        float4*       xsp = (float4*)xs;
        for (int i = t; i < TT * 2 / 4; i += 192) xsp[i] = xp[i];
    }
    if (t < HH) { h1b[0][t] = 0.f; h1b[1][t] = 0.f; h2b[t] = 0.f; fwS[t] = fcw[t]; }
    xgb[0][t] = 0.f; xgb[1][t] = 0.f;

    float hown = 0.f;   // wave0: h1[j];  wave2: h2[j]

    for (int i = 0; i < TT + 2; ++i) {
        __syncthreads();
        const bool act = (wv == 0) ? (i < TT)
                       : (wv == 1) ? (i >= 1 && i < TT + 1)
                                   : (i >= 2);
        if (act) {
            float x0 = 0.f, x1 = 0.f, g0 = 0.f, g1 = 0.f, g2 = 0.f;
            if (wv == 0) { x0 = xs[2*i]; x1 = xs[2*i + 1]; }
            if (wv == 2) {
                const float* xg = xgb[(i - 2) & 1];
                g0 = xg[j]; g1 = xg[HH + j]; g2 = xg[2*HH + j];
            }
            const float4* hb = (wv == 2) ? (const float4*)h2b
                                         : (const float4*)h1b[(i - 1) & 1];
            float A0 = ba, A1 = 0.f, B0 = bbv, B1 = 0.f, C0 = bc, C1 = 0.f;
            #pragma unroll
            for (int k = 0; k < 16; k += 2) {
                float4 hA = hb[k], hB = hb[k + 1];
                DOT4(A0,       4 * k,       hA);  DOT4(A1,       4 * (k + 1), hB);
                DOT4(B0,  64 + 4 * k,       hA);  DOT4(B1,  64 + 4 * (k + 1), hB);
                DOT4(C0, 128 + 4 * k,       hA);  DOT4(C1, 128 + 4 * (k + 1), hB);
            }
            const float A = A0 + A1, Bv = B0 + B1, C = C0 + C1;

            if (wv == 0) {                       // layer-1 gates, step i
                float r = sigm (wi0*x0 + wi1*x1 + bi0 + A);
                float z = sigm (wi2*x0 + wi3*x1 + bi1 + Bv);
                float n = ftanh(wi4*x0 + wi5*x1 + bi2 + r * C);
                hown = (1.f - z) * n + z * hown;
                h1b[i & 1][j] = hown;
            } else if (wv == 1) {                // xg for step i-1
                float* xg = xgb[(i - 1) & 1];
                xg[j] = A; xg[HH + j] = Bv; xg[2*HH + j] = C;
            } else {                             // layer-2 gates, step i-2
                float r = sigm (g0 + A);
                float z = sigm (g1 + Bv);
                float n = ftanh(g2 + r * C);
                hown = (1.f - z) * n + z * hown;
                h2b[j] = hown;
                ring[(i - 2) & 127][j] = hown;
            }
        }
        // fc-head flush: wave1, every 64 iters, 64 finished timesteps
        if (wv == 1 && i >= 66 && ((i - 66) & 63) == 0) {
            const int tt = ((i - 66) >> 6) * 64 + j;
            const float* rr = ring[tt & 127];
            float acc0 = 0.f, acc1 = 0.f;
            #pragma unroll
            for (int k = 0; k < 64; k += 2) {
                acc0 += rr[k]     * fwS[k];
                acc1 += rr[k + 1] * fwS[k + 1];
            }
            out[(size_t)b * TT + tt] = acc0 + acc1 + fcbv;
        }
    }
    __syncthreads();
    if (wv == 1) {                                // final chunk: t = 1984..2047
        const int tt = 31 * 64 + j;
        const float* rr = ring[tt & 127];
        float acc0 = 0.f, acc1 = 0.f;
        #pragma unroll
        for (int k = 0; k < 64; k += 2) {
            acc0 += rr[k]     * fwS[k];
            acc1 += rr[k + 1] * fwS[k + 1];
        }
        out[(size_t)b * TT + tt] = acc0 + acc1 + fcbv;
    }
}

extern "C" void kernel_launch(void* const* d_in, const int* in_sizes, int n_in,
                              void* d_out, int out_size, void* d_ws, size_t ws_size,
                              hipStream_t stream) {
    const float* x    = (const float*)d_in[0];
    const float* Wih0 = (const float*)d_in[1];
    const float* Whh0 = (const float*)d_in[2];
    const float* bih0 = (const float*)d_in[3];
    const float* bhh0 = (const float*)d_in[4];
    const float* Wih1 = (const float*)d_in[5];
    const float* Whh1 = (const float*)d_in[6];
    const float* bih1 = (const float*)d_in[7];
    const float* bhh1 = (const float*)d_in[8];
    const float* fcw  = (const float*)d_in[9];
    const float* fcb  = (const float*)d_in[10];
    float* out = (float*)d_out;

    gru_fused<<<BB, 192, 0, stream>>>(x, Wih0, Whh0, bih0, bhh0,
                                      Wih1, Whh1, bih1, bhh1, fcw, fcb, out);
}

// Round 7
// 2122.659 us; speedup vs baseline: 1.6816x; 1.1105x over previous
//
#include <hip/hip_runtime.h>

#define BB 128
#define TT 2048
#define HH 64

__device__ __forceinline__ float sigm(float v) {
    return __builtin_amdgcn_rcpf(1.0f + __expf(-v));
}
__device__ __forceinline__ float ftanh(float v) {
    float e = __expf(-2.0f * fabsf(v));
    float r = (1.0f - e) * __builtin_amdgcn_rcpf(1.0f + e);
    return copysignf(r, v);
}

#define PIN4(v) asm volatile("" : "+v"((v).x), "+v"((v).y), "+v"((v).z), "+v"((v).w))

// 64 blocks x 384 threads (6 waves); each block runs TWO batches (2*blk, 2*blk+1).
// Wave (s,q) = (wv>>1, wv&1): stage s in {Whh0, Wih1, Whh1}, K-half q.
// Each lane owns rows {j, 64+j, 128+j} x cols [q*32,q*32+32) = 96 floats (24 float4)
// -> under the ~130-VGPR allocation cap observed in R2-R6, so the weights can
// actually stay register-resident; the same registers serve BOTH batches.
// Per iteration i (2 barriers):
//   PhaseA: stage dots for both batches (partials -> pg LDS)
//     s=0: hg1(i) from h1(i-1);  s=1: xg(i-1) from h1(i-1) [parity];
//     s=2: hg2(i-2) from h2(i-3)
//   PhaseB: wv0/1: L1 gates batch wv -> h1(i); wv2/3: L2 gates -> h2(i-2),
//     ring store; wv4/5: fc-head flush of 64 outputs every 64 iters.
__global__ __launch_bounds__(384)
void gru_fused(const float* __restrict__ x,
               const float* __restrict__ Wih0, const float* __restrict__ Whh0,
               const float* __restrict__ bih0, const float* __restrict__ bhh0,
               const float* __restrict__ Wih1, const float* __restrict__ Whh1,
               const float* __restrict__ bih1, const float* __restrict__ bhh1,
               const float* __restrict__ fcw, const float* __restrict__ fcb,
               float* __restrict__ out)
{
    const int t   = threadIdx.x;
    const int wv  = t >> 6;         // 0..5
    const int j   = t & 63;
    const int s   = wv >> 1;        // stage
    const int q   = wv & 1;         // K-half
    const int blk = blockIdx.x;

    __shared__ __align__(16) float xs[2 * TT * 2];      // 32 KB (2 batches, contiguous)
    __shared__ __align__(16) float h1b[2][HH];
    __shared__ __align__(16) float h2b[2][HH];
    __shared__ __align__(16) float pg0[2][2][3 * HH];   // [batch][half][row]
    __shared__ __align__(16) float pg2[2][2][3 * HH];
    __shared__ __align__(16) float pg1[2][2][2][3 * HH];// [parity][batch][half][row]
    __shared__ __align__(16) float fwS[HH];
    __shared__ float ring[2][128][65];                  // 66.6 KB

    // ---- this wave's 96 weight floats ----
    const float* Wm = (s == 0) ? Whh0 : (s == 1) ? Wih1 : Whh1;
    float4 w[24];
    #pragma unroll
    for (int r = 0; r < 3; ++r) {
        const float4* p = (const float4*)(Wm + (size_t)(r * HH + j) * HH + q * 32);
        #pragma unroll
        for (int c = 0; c < 8; ++c) w[r * 8 + c] = p[c];
    }
    #pragma unroll
    for (int k = 0; k < 24; ++k) PIN4(w[k]);

    // gate-wave constants
    float wi0=0, wi1=0, wi2=0, wi3=0, wi4=0, wi5=0;
    float gb0=0, gb1=0, gb2=0, gb3=0, gb4=0, gb5=0;
    if (wv < 2) {               // L1 gates: Wih0 cols + bih0 + bhh0
        wi0 = Wih0[j*2];        wi1 = Wih0[j*2 + 1];
        wi2 = Wih0[(HH+j)*2];   wi3 = Wih0[(HH+j)*2 + 1];
        wi4 = Wih0[(2*HH+j)*2]; wi5 = Wih0[(2*HH+j)*2 + 1];
        gb0 = bih0[j]; gb1 = bih0[HH + j]; gb2 = bih0[2*HH + j];
        gb3 = bhh0[j]; gb4 = bhh0[HH + j]; gb5 = bhh0[2*HH + j];
    } else if (wv < 4) {        // L2 gates: bih1 + bhh1
        gb0 = bih1[j]; gb1 = bih1[HH + j]; gb2 = bih1[2*HH + j];
        gb3 = bhh1[j]; gb4 = bhh1[HH + j]; gb5 = bhh1[2*HH + j];
    }
    const float fcbv = fcb[0];

    // ---- preload x (both batches contiguous), zero state ----
    {
        const float4* xp  = (const float4*)(x + (size_t)(2 * blk) * TT * 2);
        float4*       xsp = (float4*)xs;
        for (int i2 = t; i2 < 2 * TT * 2 / 4; i2 += 384) xsp[i2] = xp[i2];
    }
    if (t < 2 * HH) { ((float*)h1b)[t] = 0.f; ((float*)h2b)[t] = 0.f; }
    if (t < HH) fwS[t] = fcw[t];

    float hreg0 = 0.f, hreg1 = 0.f;  // wv0/1: h1[bb][j]; wv2/3: h2[bb][j] (one used)

    for (int i = 0; i < TT + 2; ++i) {
        __syncthreads();   // B1: prev PhaseB h-writes visible

        // ---------------- Phase A: partial dots, both batches ----------------
        const bool actA = (s == 0) ? (i < TT)
                        : (s == 1) ? (i >= 1 && i <= TT)
                                   : (i >= 2);
        if (actA) {
            #pragma unroll
            for (int bb = 0; bb < 2; ++bb) {
                const float4* hp = (const float4*)((s < 2) ? h1b[bb] : h2b[bb]) + q * 8;
                float d0a = 0.f, d0b = 0.f, d1a = 0.f, d1b = 0.f, d2a = 0.f, d2b = 0.f;
                #pragma unroll
                for (int c = 0; c < 8; c += 2) {
                    float4 hA = hp[c], hB = hp[c + 1];
                    d0a += w[c     ].x*hA.x + w[c     ].y*hA.y + w[c     ].z*hA.z + w[c     ].w*hA.w;
                    d0b += w[c + 1 ].x*hB.x + w[c + 1 ].y*hB.y + w[c + 1 ].z*hB.z + w[c + 1 ].w*hB.w;
                    d1a += w[8 + c ].x*hA.x + w[8 + c ].y*hA.y + w[8 + c ].z*hA.z + w[8 + c ].w*hA.w;
                    d1b += w[9 + c ].x*hB.x + w[9 + c ].y*hB.y + w[9 + c ].z*hB.z + w[9 + c ].w*hB.w;
                    d2a += w[16 + c].x*hA.x + w[16 + c].y*hA.y + w[16 + c].z*hA.z + w[16 + c].w*hA.w;
                    d2b += w[17 + c].x*hB.x + w[17 + c].y*hB.y + w[17 + c].z*hB.z + w[17 + c].w*hB.w;
                }
                float* dst = (s == 0) ? &pg0[bb][q][0]
                           : (s == 1) ? &pg1[(i - 1) & 1][bb][q][0]
                                      : &pg2[bb][q][0];
                dst[j]          = d0a + d0b;
                dst[HH + j]     = d1a + d1b;
                dst[2*HH + j]   = d2a + d2b;
            }
        }
        __syncthreads();   // B2: partials visible

        // ---------------- Phase B: gate combines ----------------
        if (wv < 2) {
            if (i < TT) {                          // L1 gates, batch wv, step i
                const int bb = wv;
                float A  = pg0[bb][0][j]        + pg0[bb][1][j]        + gb3;
                float Bv = pg0[bb][0][HH + j]   + pg0[bb][1][HH + j]   + gb4;
                float C  = pg0[bb][0][2*HH + j] + pg0[bb][1][2*HH + j] + gb5;
                float x0 = xs[bb * TT * 2 + 2*i], x1 = xs[bb * TT * 2 + 2*i + 1];
                float r = sigm (wi0*x0 + wi1*x1 + gb0 + A);
                float z = sigm (wi2*x0 + wi3*x1 + gb1 + Bv);
                float n = ftanh(wi4*x0 + wi5*x1 + gb2 + r * C);
                float& h = (bb == 0) ? hreg0 : hreg1;
                h = (1.f - z) * n + z * h;
                h1b[bb][j] = h;
            }
        } else if (wv < 4) {
            if (i >= 2) {                          // L2 gates, batch wv-2, step i-2
                const int bb = wv - 2;
                const float* x0h = pg1[i & 1][bb][0];
                const float* x1h = pg1[i & 1][bb][1];
                float xr = x0h[j]        + x1h[j]        + gb0;
                float xz = x0h[HH + j]   + x1h[HH + j]   + gb1;
                float xn = x0h[2*HH + j] + x1h[2*HH + j] + gb2;
                float hr = pg2[bb][0][j]        + pg2[bb][1][j]        + gb3;
                float hz = pg2[bb][0][HH + j]   + pg2[bb][1][HH + j]   + gb4;
                float hn = pg2[bb][0][2*HH + j] + pg2[bb][1][2*HH + j] + gb5;
                float r = sigm (xr + hr);
                float z = sigm (xz + hz);
                float n = ftanh(xn + r * hn);
                float& h = (bb == 0) ? hreg0 : hreg1;
                h = (1.f - z) * n + z * h;
                h2b[bb][j] = h;
                ring[bb][(i - 2) & 127][j] = h;
            }
        } else {
            if (i >= 66 && ((i - 66) & 63) == 0) { // fc flush, batch wv-4
                const int bb = wv - 4;
                const int tt = ((i - 66) >> 6) * 64 + j;
                const float* rr = ring[bb][tt & 127];
                float acc0 = 0.f, acc1 = 0.f;
                #pragma unroll
                for (int k = 0; k < 64; k += 2) {
                    acc0 += rr[k]     * fwS[k];
                    acc1 += rr[k + 1] * fwS[k + 1];
                }
                out[(size_t)(2 * blk + bb) * TT + tt] = acc0 + acc1 + fcbv;
            }
        }
    }
    __syncthreads();
    if (wv >= 4) {                                 // final chunk: steps 1984..2047
        const int bb = wv - 4;
        const int tt = 31 * 64 + j;
        const float* rr = ring[bb][tt & 127];
        float acc0 = 0.f, acc1 = 0.f;
        #pragma unroll
        for (int k = 0; k < 64; k += 2) {
            acc0 += rr[k]     * fwS[k];
            acc1 += rr[k + 1] * fwS[k + 1];
        }
        out[(size_t)(2 * blk + bb) * TT + tt] = acc0 + acc1 + fcbv;
    }
}

extern "C" void kernel_launch(void* const* d_in, const int* in_sizes, int n_in,
                              void* d_out, int out_size, void* d_ws, size_t ws_size,
                              hipStream_t stream) {
    const float* x    = (const float*)d_in[0];
    const float* Wih0 = (const float*)d_in[1];
    const float* Whh0 = (const float*)d_in[2];
    const float* bih0 = (const float*)d_in[3];
    const float* bhh0 = (const float*)d_in[4];
    const float* Wih1 = (const float*)d_in[5];
    const float* Whh1 = (const float*)d_in[6];
    const float* bih1 = (const float*)d_in[7];
    const float* bhh1 = (const float*)d_in[8];
    const float* fcw  = (const float*)d_in[9];
    const float* fcb  = (const float*)d_in[10];
    float* out = (float*)d_out;

    gru_fused<<<BB / 2, 384, 0, stream>>>(x, Wih0, Whh0, bih0, bhh0,
                                          Wih1, Whh1, bih1, bhh1, fcw, fcb, out);
}

// Round 8
// 1577.400 us; speedup vs baseline: 2.2628x; 1.3457x over previous
//
#include <hip/hip_runtime.h>

#define BB 128
#define TT 2048
#define HH 64

__device__ __forceinline__ float sigm(float v) {
    return __builtin_amdgcn_rcpf(1.0f + __expf(-v));
}
__device__ __forceinline__ float ftanh(float v) {
    float e = __expf(-2.0f * fabsf(v));
    float r = (1.0f - e) * __builtin_amdgcn_rcpf(1.0f + e);
    return copysignf(r, v);
}

#define PIN4(v) asm volatile("" : "+v"((v).x), "+v"((v).y), "+v"((v).z), "+v"((v).w))

// One block per batch, 12 waves. Lane (4g+q) of stage-wave (s,sw) owns
// gate-rows {d, 64+d, 128+d} (d = sw*16+g) x cols [16q,16q+16) of its stage
// matrix = 48 floats/lane -- the only footprint (R5, F=64, VGPR 76) the RA
// has ever kept resident; R2-R7 proved F>=96 always spills -> L2 refetch.
// K-quarter partials combine via __shfl_xor(1),(2) IN-WAVE (DPP, no LDS),
// so each stage computes dots AND gates locally: ONE barrier per iteration.
//   s=0: h1(i)  = GRU1(h1(i-1), x(i))          [h1b parity]
//   s=1: xg(i-1)= Wih1*h1(i-1)+bih1            [xgb parity]
//   s=2: h2(i-2)= GRU2(h2(i-3), xg(i-2))       [h2b parity, ring store]
// fc head: wave 7 flushes 64 outputs every 64 iters from the 128-slot ring.
__global__ __launch_bounds__(768)
void gru_fused(const float* __restrict__ x,
               const float* __restrict__ Wih0, const float* __restrict__ Whh0,
               const float* __restrict__ bih0, const float* __restrict__ bhh0,
               const float* __restrict__ Wih1, const float* __restrict__ Whh1,
               const float* __restrict__ bih1, const float* __restrict__ bhh1,
               const float* __restrict__ fcw, const float* __restrict__ fcb,
               float* __restrict__ out)
{
    const int t  = threadIdx.x;
    const int w  = t >> 6;          // wave 0..11
    const int j  = t & 63;          // lane
    const int s  = w >> 2;          // stage 0..2
    const int sw = w & 3;           // dim block
    const int g  = j >> 2;          // local dim 0..15
    const int q  = j & 3;           // K-quarter
    const int d  = sw * 16 + g;     // dim 0..63
    const int b  = blockIdx.x;

    __shared__ __align__(16) float xs[TT * 2];       // 16 KB input
    __shared__ __align__(16) float h1b[2][HH];       // parity
    __shared__ __align__(16) float h2b[2][HH];       // parity
    __shared__ __align__(16) float xgb[2][3 * HH];   // parity
    __shared__ __align__(16) float fwS[HH];
    __shared__ float ring[128][65];                  // h2 history, stride 65

    // ---- 48 resident weight floats: 3 rows x 16 cols ----
    const float* Wm = (s == 0) ? Whh0 : (s == 1) ? Wih1 : Whh1;
    float4 wq[12];
    #pragma unroll
    for (int r = 0; r < 3; ++r) {
        const float4* p = (const float4*)(Wm + (size_t)(r * HH + d) * HH + q * 16);
        #pragma unroll
        for (int c = 0; c < 4; ++c) wq[r * 4 + c] = p[c];
    }
    #pragma unroll
    for (int k = 0; k < 12; ++k) PIN4(wq[k]);

    // biases (added AFTER the shfl combine, so loaded once per lane)
    float kb0, kb1, kb2, bi2 = 0.f;
    if (s == 0) {            // r,z: fold bih0+bhh0; n: bhh0 inside r*(), bih0 outside
        kb0 = bhh0[d] + bih0[d];
        kb1 = bhh0[HH + d] + bih0[HH + d];
        kb2 = bhh0[2 * HH + d];
        bi2 = bih0[2 * HH + d];
    } else if (s == 1) {
        kb0 = bih1[d]; kb1 = bih1[HH + d]; kb2 = bih1[2 * HH + d];
    } else {
        kb0 = bhh1[d]; kb1 = bhh1[HH + d]; kb2 = bhh1[2 * HH + d];
    }
    float wi0 = 0, wi1 = 0, wi2 = 0, wi3 = 0, wi4 = 0, wi5 = 0;
    if (s == 0) {
        wi0 = Wih0[d * 2];            wi1 = Wih0[d * 2 + 1];
        wi2 = Wih0[(HH + d) * 2];     wi3 = Wih0[(HH + d) * 2 + 1];
        wi4 = Wih0[(2 * HH + d) * 2]; wi5 = Wih0[(2 * HH + d) * 2 + 1];
    }
    const float fcbv = fcb[0];

    // ---- preload x, zero state ----
    {
        const float4* xp  = (const float4*)(x + (size_t)b * TT * 2);
        float4*       xsp = (float4*)xs;
        for (int i2 = t; i2 < TT * 2 / 4; i2 += 768) xsp[i2] = xp[i2];
    }
    if (t < 2 * HH) { ((float*)h1b)[t] = 0.f; ((float*)h2b)[t] = 0.f; }
    if (t < HH) fwS[t] = fcw[t];

    float hreg = 0.f;   // s0: h1[d]; s2: h2[d] (tracked redundantly by 4 lanes)

#define ROWDOT(outv, base)                                                     \
    do {                                                                       \
        float u0 = wq[base].x*hA.x + wq[base].y*hA.y + wq[base].z*hA.z + wq[base].w*hA.w; \
        float u1 = wq[base+1].x*hB.x + wq[base+1].y*hB.y + wq[base+1].z*hB.z + wq[base+1].w*hB.w; \
        float u2 = wq[base+2].x*hC.x + wq[base+2].y*hC.y + wq[base+2].z*hC.z + wq[base+2].w*hC.w; \
        float u3 = wq[base+3].x*hD.x + wq[base+3].y*hD.y + wq[base+3].z*hD.z + wq[base+3].w*hD.w; \
        outv = (u0 + u1) + (u2 + u3);                                          \
    } while (0)

    for (int i = 0; i < TT + 2; ++i) {
        __syncthreads();
        const bool act = (s == 0) ? (i < TT)
                       : (s == 1) ? (i >= 1 && i <= TT)
                                  : (i >= 2);
        if (act) {
            const float4* hp = (const float4*)((s < 2) ? h1b[(i - 1) & 1]
                                                       : h2b[(i - 1) & 1]) + q * 4;
            float4 hA = hp[0], hB = hp[1], hC = hp[2], hD = hp[3];
            float a0, a1, a2;
            ROWDOT(a0, 0); ROWDOT(a1, 4); ROWDOT(a2, 8);
            // combine K-quarters in-wave (lanes 4g..4g+3), then biases once
            a0 += __shfl_xor(a0, 1); a0 += __shfl_xor(a0, 2);
            a1 += __shfl_xor(a1, 1); a1 += __shfl_xor(a1, 2);
            a2 += __shfl_xor(a2, 1); a2 += __shfl_xor(a2, 2);
            a0 += kb0; a1 += kb1; a2 += kb2;

            if (s == 0) {                        // layer-1 gates, step i
                float x0 = xs[2 * i], x1 = xs[2 * i + 1];
                float rr = sigm (fmaf(wi0, x0, fmaf(wi1, x1, a0)));
                float zz = sigm (fmaf(wi2, x0, fmaf(wi3, x1, a1)));
                float nn = ftanh(fmaf(wi4, x0, fmaf(wi5, x1, bi2)) + rr * a2);
                hreg = (1.f - zz) * nn + zz * hreg;
                if (q == 0) h1b[i & 1][d] = hreg;
            } else if (s == 1) {                 // xg(i-1) producer
                if (q == 0) {
                    float* xg = xgb[(i - 1) & 1];
                    xg[d] = a0; xg[HH + d] = a1; xg[2 * HH + d] = a2;
                }
            } else {                             // layer-2 gates, step i-2
                const float* xg = xgb[(i - 2) & 1];
                float rr = sigm (xg[d]          + a0);
                float zz = sigm (xg[HH + d]     + a1);
                float nn = ftanh(xg[2 * HH + d] + rr * a2);
                hreg = (1.f - zz) * nn + zz * hreg;
                if (q == 0) {
                    h2b[i & 1][d] = hreg;
                    ring[(i - 2) & 127][d] = hreg;
                }
            }
        }
        // fc-head flush: wave 7, every 64 iters, 64 finished timesteps
        if (w == 7 && i >= 66 && ((i - 66) & 63) == 0) {
            const int tt = ((i - 66) >> 6) * 64 + j;
            const float* rr2 = ring[tt & 127];
            float acc0 = 0.f, acc1 = 0.f;
            #pragma unroll
            for (int k = 0; k < 64; k += 2) {
                acc0 += rr2[k]     * fwS[k];
                acc1 += rr2[k + 1] * fwS[k + 1];
            }
            out[(size_t)b * TT + tt] = acc0 + acc1 + fcbv;
        }
    }
    __syncthreads();
    if (w == 7) {                                // final chunk: t = 1984..2047
        const int tt = 31 * 64 + j;
        const float* rr2 = ring[tt & 127];
        float acc0 = 0.f, acc1 = 0.f;
        #pragma unroll
        for (int k = 0; k < 64; k += 2) {
            acc0 += rr2[k]     * fwS[k];
            acc1 += rr2[k + 1] * fwS[k + 1];
        }
        out[(size_t)b * TT + tt] = acc0 + acc1 + fcbv;
    }
#undef ROWDOT
}

extern "C" void kernel_launch(void* const* d_in, const int* in_sizes, int n_in,
                              void* d_out, int out_size, void* d_ws, size_t ws_size,
                              hipStream_t stream) {
    const float* x    = (const float*)d_in[0];
    const float* Wih0 = (const float*)d_in[1];
    const float* Whh0 = (const float*)d_in[2];
    const float* bih0 = (const float*)d_in[3];
    const float* bhh0 = (const float*)d_in[4];
    const float* Wih1 = (const float*)d_in[5];
    const float* Whh1 = (const float*)d_in[6];
    const float* bih1 = (const float*)d_in[7];
    const float* bhh1 = (const float*)d_in[8];
    const float* fcw  = (const float*)d_in[9];
    const float* fcb  = (const float*)d_in[10];
    float* out = (float*)d_out;

    gru_fused<<<BB, 768, 0, stream>>>(x, Wih0, Whh0, bih0, bhh0,
                                      Wih1, Whh1, bih1, bhh1, fcw, fcb, out);
}